// Round 5
// baseline (320.170 us; speedup 1.0000x reference)
//
#include <hip/hip_runtime.h>
#include <math.h>

typedef unsigned short u16;
typedef unsigned int u32;

#define Bb   16
#define Hh   8
#define KD   32
#define DV   128
#define DIM  512
#define Nn   1024
#define OQKV 192
// SCALE * log2(e): QK logits emerge in log2-domain; softmax exp -> v_exp_f32 (2^x)
#define SCALE2 0.25503490221320355f

typedef short bf16x8 __attribute__((ext_vector_type(8)));   // 4 VGPRs = 8 bf16
typedef float f32x16 __attribute__((ext_vector_type(16)));  // 32x32 C/D frag

#define MFMA32(a, b, c) __builtin_amdgcn_mfma_f32_32x32x16_bf16(a, b, c, 0, 0, 0)

__device__ __forceinline__ float fexp2(float x) {
#if __has_builtin(__builtin_amdgcn_exp2f)
  return __builtin_amdgcn_exp2f(x);
#else
  return exp2f(x);
#endif
}

// round-to-nearest bf16 via +0x8000 (half-up)
__device__ __forceinline__ u16 f2bf_rn(float f) {
  return (u16)((__float_as_uint(f) + 0x8000u) >> 16);
}
// pack two floats -> two bf16 in one dword: v_add x2 + v_perm
__device__ __forceinline__ u32 pkrn(float lo, float hi) {
  u32 a = __float_as_uint(lo) + 0x8000u;
  u32 b = __float_as_uint(hi) + 0x8000u;
  return __builtin_amdgcn_perm(b, a, 0x07060302);
}

// ---------------------------------------------------------------------------
// Kernel A: QKV bf16 MFMA GEMM (unchanged except Q scale = SCALE*log2e).
//   Qb[bh][n][32c], Kb[bh][n][32c], Vb[bh][d][1024n].
// ---------------------------------------------------------------------------
__global__ __launch_bounds__(256) void qkv_kernel(
    const float* __restrict__ x, const float* __restrict__ w,
    const float* __restrict__ bias, u16* __restrict__ Qb,
    u16* __restrict__ Kb, u16* __restrict__ Vb) {
  const int nt = blockIdx.x, bh = blockIdx.y;
  const int b = bh >> 3, h = bh & 7;
  const int tid = threadIdx.x;
  const int wid = tid >> 6, lane = tid & 63;
  const int r32 = lane & 31, hh = lane >> 5;
  const int n0 = nt * 128;

  __shared__ __align__(16) u16 Ws[192 * 72];  // [o][c] bf16
  __shared__ __align__(16) u16 Xs[128 * 72];  // [n][c] bf16

  const float* wp = w + (size_t)h * OQKV * 64;
  #pragma unroll
  for (int i = 0; i < 12; ++i) {
    int idx = i * 256 + tid;
    int o = idx >> 4, c4 = (idx & 15) * 4;
    float4 wv = *(const float4*)&wp[o * 64 + c4];
    uint2 pk; pk.x = pkrn(wv.x, wv.y); pk.y = pkrn(wv.z, wv.w);
    *(uint2*)&Ws[o * 72 + c4] = pk;
  }
  const float* xp = x + ((size_t)b * DIM + h * 64) * Nn + n0;
  #pragma unroll
  for (int i = 0; i < 8; ++i) {
    int idx = i * 256 + tid;
    int c = idx >> 5, n4 = (idx & 31) * 4;
    float4 xv = *(const float4*)&xp[(size_t)c * Nn + n4];
    Xs[(n4 + 0) * 72 + c] = f2bf_rn(xv.x);
    Xs[(n4 + 1) * 72 + c] = f2bf_rn(xv.y);
    Xs[(n4 + 2) * 72 + c] = f2bf_rn(xv.z);
    Xs[(n4 + 3) * 72 + c] = f2bf_rn(xv.w);
  }
  __syncthreads();

  f32x16 acc[6];
  #pragma unroll
  for (int t = 0; t < 6; ++t)
    #pragma unroll
    for (int r = 0; r < 16; ++r) acc[t][r] = 0.0f;

  const int nw = wid * 32;
  #pragma unroll
  for (int k = 0; k < 4; ++k) {
    const int ko = k * 16 + hh * 8;
    bf16x8 xb = *(const bf16x8*)&Xs[(nw + r32) * 72 + ko];
    #pragma unroll
    for (int t = 0; t < 6; ++t) {
      bf16x8 wa = *(const bf16x8*)&Ws[(t * 32 + r32) * 72 + ko];
      acc[t] = MFMA32(wa, xb, acc[t]);
    }
  }

  const int n = n0 + nw + r32;
  const float* bp = bias + h * OQKV;
  #pragma unroll
  for (int t = 0; t < 6; ++t) {
    #pragma unroll
    for (int g = 0; g < 4; ++g) {
      const int ob = t * 32 + 8 * g + 4 * hh;
      float4 bv = *(const float4*)&bp[ob];
      float v0 = acc[t][4 * g + 0] + bv.x;
      float v1 = acc[t][4 * g + 1] + bv.y;
      float v2 = acc[t][4 * g + 2] + bv.z;
      float v3 = acc[t][4 * g + 3] + bv.w;
      if (t == 0) {                       // Q (c = ob), scaled by SCALE*log2e
        uint2 pk;
        pk.x = pkrn(v0 * SCALE2, v1 * SCALE2);
        pk.y = pkrn(v2 * SCALE2, v3 * SCALE2);
        *(uint2*)&Qb[((size_t)bh * Nn + n) * 32 + ob] = pk;
      } else if (t == 1) {                // K (c = ob - 32)
        uint2 pk; pk.x = pkrn(v0, v1); pk.y = pkrn(v2, v3);
        *(uint2*)&Kb[((size_t)bh * Nn + n) * 32 + ob - 32] = pk;
      } else {                            // V (d = ob - 64), row-major [d][n]
        const int d = ob - 64;
        Vb[((size_t)bh * DV + d + 0) * Nn + n] = f2bf_rn(v0);
        Vb[((size_t)bh * DV + d + 1) * Nn + n] = f2bf_rn(v1);
        Vb[((size_t)bh * DV + d + 2) * Nn + n] = f2bf_rn(v2);
        Vb[((size_t)bh * DV + d + 3) * Nn + n] = f2bf_rn(v3);
      }
    }
  }
}

// ---------------------------------------------------------------------------
// Kernel B: barrier-free MFMA flash attention.
//   S^T[n][m] = K(A) x Q(B)   (Q/K frags direct from global, frag-order)
//   P C-layout -> A-layout via one shfl_xor(32) exchange (same algebra as
//   the validated B-layout exchange)
//   O[m][d] += P(A) x V(B)    (V B-frags DIRECT from global Vb[d][n] —
//   16 B contiguous; chunk stays hot in L1, shared by the 4 waves)
// No __syncthreads anywhere; waves free-run. lsum broadcast via wave-
// private LDS at the end. XCD swizzle: all 8 m-tiles of a bh on one XCD.
// ---------------------------------------------------------------------------
__global__ __launch_bounds__(256) void attn_kernel(
    const u16* __restrict__ Qb, const u16* __restrict__ Kb,
    const u16* __restrict__ Vb, u16* __restrict__ Ot2) {
  const int blk = blockIdx.x;            // 0..1023
  const int xcd = blk & 7, j = blk >> 3; // round-robin heuristic: i%8 = XCD
  const int bh = (xcd << 4) | (j >> 3);  // 16 bh per XCD
  const int mt = j & 7;
  const int tid = threadIdx.x;
  const int wid = tid >> 6, lane = tid & 63;
  const int r32 = lane & 31, hh = lane >> 5;
  const int mw = mt * 128 + wid * 32;    // wave's m base

  __shared__ float Lw[4][32];            // per-wave 1/lsum broadcast

  // Q B-frags: lane = col m, k = c = 16s + 8hh + j (16 B contiguous)
  const u16* qp = Qb + ((size_t)bh * Nn + mw + r32) * 32;
  const bf16x8 qb0 = *(const bf16x8*)&qp[hh * 8];
  const bf16x8 qb1 = *(const bf16x8*)&qp[16 + hh * 8];

  const u16* kbase = Kb + (size_t)bh * Nn * 32;
  const u16* vbase = Vb + (size_t)bh * DV * Nn;

  f32x16 o[4];                           // D[m][d]: col d = t*32+r32
  #pragma unroll
  for (int t = 0; t < 4; ++t)
    #pragma unroll
    for (int r = 0; r < 16; ++r) o[t][r] = 0.0f;
  float lsum = 0.0f;

  for (int ch = 0; ch < Nn / 32; ++ch) {
    const int n0 = ch * 32;

    // K A-frags direct from global: row n = n0 + r32
    const u16* kp = kbase + (size_t)(n0 + r32) * 32;
    bf16x8 ka0 = *(const bf16x8*)&kp[hh * 8];
    bf16x8 ka1 = *(const bf16x8*)&kp[16 + hh * 8];

    f32x16 s;
    #pragma unroll
    for (int r = 0; r < 16; ++r) s[r] = 0.0f;
    s = MFMA32(ka0, qb0, s);
    s = MFMA32(ka1, qb1, s);

    // softmax numerator: p = 2^s (log2e pre-folded); no max needed (|s| small)
    float csum = 0.0f;
    #pragma unroll
    for (int r = 0; r < 16; ++r) { s[r] = fexp2(s[r]); csum += s[r]; }
    lsum += csum;

    // pack P (C-layout: lane=col m, rows n=8g+4hh+i) and exchange halves
    // -> A-operand frags (lane=row m, k=n=16s+8hh+j)
    u32 Pk[8], Rk[8];
    #pragma unroll
    for (int g = 0; g < 4; ++g) {
      Pk[2 * g]     = pkrn(s[4 * g + 0], s[4 * g + 1]);
      Pk[2 * g + 1] = pkrn(s[4 * g + 2], s[4 * g + 3]);
    }
    #pragma unroll
    for (int i = 0; i < 8; ++i) Rk[i] = __shfl_xor(Pk[i], 32, 64);

    union { u32 d[4]; bf16x8 v; } pa0, pa1;
    pa0.d[0] = hh ? Rk[2] : Pk[0];
    pa0.d[1] = hh ? Rk[3] : Pk[1];
    pa0.d[2] = hh ? Pk[2] : Rk[0];
    pa0.d[3] = hh ? Pk[3] : Rk[1];
    pa1.d[0] = hh ? Rk[6] : Pk[4];
    pa1.d[1] = hh ? Rk[7] : Pk[5];
    pa1.d[2] = hh ? Pk[6] : Rk[4];
    pa1.d[3] = hh ? Pk[7] : Rk[5];

    // PV: O[m][d] += P(A) x V(B); V B-frags direct from global Vb[d][n]
    const u16* vp = vbase + n0;
    #pragma unroll
    for (int t = 0; t < 4; ++t) {
      const u16* vr = vp + (size_t)(t * 32 + r32) * Nn;
      bf16x8 vb0 = *(const bf16x8*)&vr[hh * 8];
      bf16x8 vb1 = *(const bf16x8*)&vr[16 + hh * 8];
      o[t] = MFMA32(pa0.v, vb0, o[t]);
      o[t] = MFMA32(pa1.v, vb1, o[t]);
    }
  }

  // lsum: lane holds partial over its n-half for col m=r32; combine halves
  lsum += __shfl_xor(lsum, 32, 64);
  Lw[wid][r32] = 1.0f / lsum;            // wave-private; no barrier needed
  asm volatile("s_waitcnt lgkmcnt(0)" ::: "memory");

  // epilogue: relu(o * invl) -> Ot2[b][h*128+d][m] (lane owns d-column)
  #pragma unroll
  for (int t = 0; t < 4; ++t) {
    u16* orow = Ot2 + ((size_t)bh * DV + t * 32 + r32) * Nn;
    #pragma unroll
    for (int g = 0; g < 4; ++g) {
      float4 iv = *(const float4*)&Lw[wid][8 * g + 4 * hh];
      float v0 = fmaxf(o[t][4 * g + 0] * iv.x, 0.0f);
      float v1 = fmaxf(o[t][4 * g + 1] * iv.y, 0.0f);
      float v2 = fmaxf(o[t][4 * g + 2] * iv.z, 0.0f);
      float v3 = fmaxf(o[t][4 * g + 3] * iv.w, 0.0f);
      uint2 pk; pk.x = pkrn(v0, v1); pk.y = pkrn(v2, v3);
      *(uint2*)&orow[mw + 8 * g + 4 * hh] = pk;
    }
  }
}

// ---------------------------------------------------------------------------
// Kernel C: proj bf16 MFMA GEMM + fused bias/BN. Ot2 is [b][ic][n]; staged
// into Os[n][ic] via u16 LDS transpose (same pattern as qkv's Xs staging).
// ---------------------------------------------------------------------------
__global__ __launch_bounds__(256) void proj_kernel(
    const u16* __restrict__ Ot2, const float* __restrict__ pw,
    const float* __restrict__ pb, const float* __restrict__ bn_g,
    const float* __restrict__ bn_b, const float* __restrict__ bn_m,
    const float* __restrict__ bn_v, float* __restrict__ out) {
  const int n0 = blockIdx.x * 128, oc0 = blockIdx.y * 128, b = blockIdx.z;
  const int tid = threadIdx.x;
  const int wid = tid >> 6, lane = tid & 63;
  const int r32 = lane & 31, hh = lane >> 5;
  const int ocw = (wid >> 1) * 64, nw = (wid & 1) * 64;

  __shared__ __align__(16) u16 Ws[128 * 40];  // [oc][ic]
  __shared__ __align__(16) u16 Os[128 * 40];  // [n][ic]

  f32x16 o[2][2];
  #pragma unroll
  for (int t = 0; t < 2; ++t)
    #pragma unroll
    for (int u = 0; u < 2; ++u)
      #pragma unroll
      for (int r = 0; r < 16; ++r) o[t][u][r] = 0.0f;

  for (int ic0 = 0; ic0 < 1024; ic0 += 32) {
    __syncthreads();
    #pragma unroll
    for (int i = 0; i < 4; ++i) {       // stage W: 128x32 fp32 -> bf16
      int idx = i * 256 + tid;
      int row = idx >> 3, icq = (idx & 7) * 4;
      float4 wv = *(const float4*)&pw[(size_t)(oc0 + row) * 1024 + ic0 + icq];
      uint2 pk; pk.x = pkrn(wv.x, wv.y); pk.y = pkrn(wv.z, wv.w);
      *(uint2*)&Ws[row * 40 + icq] = pk;
    }
    #pragma unroll
    for (int i = 0; i < 2; ++i) {       // stage Ot2 [ic][n] -> Os[n][ic]
      int idx = i * 256 + tid;          // 0..511
      int ic = idx >> 4, n8 = (idx & 15) * 8;
      uint4 ov = *(const uint4*)
          &Ot2[((size_t)b * 1024 + ic0 + ic) * Nn + n0 + n8];
      const u16* op = (const u16*)&ov;
      #pragma unroll
      for (int jj = 0; jj < 8; ++jj) Os[(n8 + jj) * 40 + ic] = op[jj];
    }
    __syncthreads();

    #pragma unroll
    for (int s = 0; s < 2; ++s) {
      const int ko = s * 16 + hh * 8;
      bf16x8 a0 = *(const bf16x8*)&Ws[(ocw + r32) * 40 + ko];
      bf16x8 a1 = *(const bf16x8*)&Ws[(ocw + 32 + r32) * 40 + ko];
      bf16x8 b0 = *(const bf16x8*)&Os[(nw + r32) * 40 + ko];
      bf16x8 b1 = *(const bf16x8*)&Os[(nw + 32 + r32) * 40 + ko];
      o[0][0] = MFMA32(a0, b0, o[0][0]);
      o[0][1] = MFMA32(a0, b1, o[0][1]);
      o[1][0] = MFMA32(a1, b0, o[1][0]);
      o[1][1] = MFMA32(a1, b1, o[1][1]);
    }
  }

  #pragma unroll
  for (int t = 0; t < 2; ++t) {
    const int obase = oc0 + ocw + t * 32 + 4 * hh;
    #pragma unroll
    for (int g = 0; g < 4; ++g) {
      const int oc = obase + 8 * g;
      float4 gv = *(const float4*)&bn_g[oc];
      float4 vv = *(const float4*)&bn_v[oc];
      float4 bv = *(const float4*)&bn_b[oc];
      float4 mv = *(const float4*)&bn_m[oc];
      float4 pv = *(const float4*)&pb[oc];
      float inv4[4], add4[4];
      inv4[0] = gv.x * rsqrtf(vv.x + 1e-5f);
      inv4[1] = gv.y * rsqrtf(vv.y + 1e-5f);
      inv4[2] = gv.z * rsqrtf(vv.z + 1e-5f);
      inv4[3] = gv.w * rsqrtf(vv.w + 1e-5f);
      add4[0] = pv.x * inv4[0] + bv.x - mv.x * inv4[0];
      add4[1] = pv.y * inv4[1] + bv.y - mv.y * inv4[1];
      add4[2] = pv.z * inv4[2] + bv.z - mv.z * inv4[2];
      add4[3] = pv.w * inv4[3] + bv.w - mv.w * inv4[3];
      #pragma unroll
      for (int u = 0; u < 2; ++u) {
        const int n = n0 + nw + u * 32 + r32;
        #pragma unroll
        for (int i = 0; i < 4; ++i) {
          float val = o[t][u][4 * g + i] * inv4[i] + add4[i];
          out[((size_t)b * DIM + oc + i) * Nn + n] = val;
        }
      }
    }
  }
}

// ---------------------------------------------------------------------------
extern "C" void kernel_launch(void* const* d_in, const int* in_sizes, int n_in,
                              void* d_out, int out_size, void* d_ws,
                              size_t ws_size, hipStream_t stream) {
  const float* x      = (const float*)d_in[0];
  const float* qkv_w  = (const float*)d_in[1];
  const float* qkv_b  = (const float*)d_in[2];
  const float* proj_w = (const float*)d_in[3];
  const float* proj_b = (const float*)d_in[4];
  const float* bn_g   = (const float*)d_in[5];
  const float* bn_b   = (const float*)d_in[6];
  const float* bn_m   = (const float*)d_in[7];
  const float* bn_v   = (const float*)d_in[8];
  float* out = (float*)d_out;

  char* ws = (char*)d_ws;
  u16* Qb  = (u16*)(ws);                 // 128*1024*32*2 =  8 MB
  u16* Kb  = (u16*)(ws + 8388608);       //                  8 MB
  u16* Vb  = (u16*)(ws + 16777216);      // 128*128*1024*2 = 32 MB
  u16* Ot2 = (u16*)(ws + 50331648);      // 16*1024*1024*2 = 32 MB  [b][ic][n]

  qkv_kernel<<<dim3(8, Bb * Hh), 256, 0, stream>>>(x, qkv_w, qkv_b, Qb, Kb, Vb);
  attn_kernel<<<dim3(1024), 256, 0, stream>>>(Qb, Kb, Vb, Ot2);
  proj_kernel<<<dim3(8, 4, Bb), 256, 0, stream>>>(
      Ot2, proj_w, proj_b, bn_g, bn_b, bn_m, bn_v, out);
}

// Round 6
// 220.294 us; speedup vs baseline: 1.4534x; 1.4534x over previous
//
#include <hip/hip_runtime.h>
#include <math.h>

typedef unsigned short u16;
typedef unsigned int u32;

#define Bb   16
#define Hh   8
#define KD   32
#define DV   128
#define DIM  512
#define Nn   1024
#define OQKV 192
// SCALE * log2(e): QK logits emerge in log2-domain; softmax exp -> v_exp_f32
#define SCALE2 0.25503490221320355f

typedef short bf16x8 __attribute__((ext_vector_type(8)));   // 4 VGPRs = 8 bf16
typedef float f32x16 __attribute__((ext_vector_type(16)));  // 32x32 C/D frag

#define MFMA32(a, b, c) __builtin_amdgcn_mfma_f32_32x32x16_bf16(a, b, c, 0, 0, 0)

__device__ __forceinline__ float fexp2(float x) {
#if __has_builtin(__builtin_amdgcn_exp2f)
  return __builtin_amdgcn_exp2f(x);
#else
  return exp2f(x);
#endif
}

__device__ __forceinline__ u16 f2bf_rn(float f) {
  return (u16)((__float_as_uint(f) + 0x8000u) >> 16);
}
__device__ __forceinline__ u32 pkrn(float lo, float hi) {
  u32 a = __float_as_uint(lo) + 0x8000u;
  u32 b = __float_as_uint(hi) + 0x8000u;
  return __builtin_amdgcn_perm(b, a, 0x07060302);
}

// ---------------------------------------------------------------------------
// Kernel A: QKV bf16 MFMA GEMM (unchanged from r5).
//   Qb[bh][n][32c] (SCALE*log2e folded), Kb[bh][n][32c], Vb[bh][d][1024n].
// ---------------------------------------------------------------------------
__global__ __launch_bounds__(256) void qkv_kernel(
    const float* __restrict__ x, const float* __restrict__ w,
    const float* __restrict__ bias, u16* __restrict__ Qb,
    u16* __restrict__ Kb, u16* __restrict__ Vb) {
  const int nt = blockIdx.x, bh = blockIdx.y;
  const int b = bh >> 3, h = bh & 7;
  const int tid = threadIdx.x;
  const int wid = tid >> 6, lane = tid & 63;
  const int r32 = lane & 31, hh = lane >> 5;
  const int n0 = nt * 128;

  __shared__ __align__(16) u16 Ws[192 * 72];  // [o][c] bf16
  __shared__ __align__(16) u16 Xs[128 * 72];  // [n][c] bf16

  const float* wp = w + (size_t)h * OQKV * 64;
  #pragma unroll
  for (int i = 0; i < 12; ++i) {
    int idx = i * 256 + tid;
    int o = idx >> 4, c4 = (idx & 15) * 4;
    float4 wv = *(const float4*)&wp[o * 64 + c4];
    uint2 pk; pk.x = pkrn(wv.x, wv.y); pk.y = pkrn(wv.z, wv.w);
    *(uint2*)&Ws[o * 72 + c4] = pk;
  }
  const float* xp = x + ((size_t)b * DIM + h * 64) * Nn + n0;
  #pragma unroll
  for (int i = 0; i < 8; ++i) {
    int idx = i * 256 + tid;
    int c = idx >> 5, n4 = (idx & 31) * 4;
    float4 xv = *(const float4*)&xp[(size_t)c * Nn + n4];
    Xs[(n4 + 0) * 72 + c] = f2bf_rn(xv.x);
    Xs[(n4 + 1) * 72 + c] = f2bf_rn(xv.y);
    Xs[(n4 + 2) * 72 + c] = f2bf_rn(xv.z);
    Xs[(n4 + 3) * 72 + c] = f2bf_rn(xv.w);
  }
  __syncthreads();

  f32x16 acc[6];
  #pragma unroll
  for (int t = 0; t < 6; ++t)
    #pragma unroll
    for (int r = 0; r < 16; ++r) acc[t][r] = 0.0f;

  const int nw = wid * 32;
  #pragma unroll
  for (int k = 0; k < 4; ++k) {
    const int ko = k * 16 + hh * 8;
    bf16x8 xb = *(const bf16x8*)&Xs[(nw + r32) * 72 + ko];
    #pragma unroll
    for (int t = 0; t < 6; ++t) {
      bf16x8 wa = *(const bf16x8*)&Ws[(t * 32 + r32) * 72 + ko];
      acc[t] = MFMA32(wa, xb, acc[t]);
    }
  }

  const int n = n0 + nw + r32;
  const float* bp = bias + h * OQKV;
  #pragma unroll
  for (int t = 0; t < 6; ++t) {
    #pragma unroll
    for (int g = 0; g < 4; ++g) {
      const int ob = t * 32 + 8 * g + 4 * hh;
      float4 bv = *(const float4*)&bp[ob];
      float v0 = acc[t][4 * g + 0] + bv.x;
      float v1 = acc[t][4 * g + 1] + bv.y;
      float v2 = acc[t][4 * g + 2] + bv.z;
      float v3 = acc[t][4 * g + 3] + bv.w;
      if (t == 0) {                       // Q, scaled by SCALE*log2e
        uint2 pk;
        pk.x = pkrn(v0 * SCALE2, v1 * SCALE2);
        pk.y = pkrn(v2 * SCALE2, v3 * SCALE2);
        *(uint2*)&Qb[((size_t)bh * Nn + n) * 32 + ob] = pk;
      } else if (t == 1) {                // K (c = ob - 32)
        uint2 pk; pk.x = pkrn(v0, v1); pk.y = pkrn(v2, v3);
        *(uint2*)&Kb[((size_t)bh * Nn + n) * 32 + ob - 32] = pk;
      } else {                            // V (d = ob - 64), row-major [d][n]
        const int d = ob - 64;
        Vb[((size_t)bh * DV + d + 0) * Nn + n] = f2bf_rn(v0);
        Vb[((size_t)bh * DV + d + 1) * Nn + n] = f2bf_rn(v1);
        Vb[((size_t)bh * DV + d + 2) * Nn + n] = f2bf_rn(v2);
        Vb[((size_t)bh * DV + d + 3) * Nn + n] = f2bf_rn(v3);
      }
    }
  }
}

// ---------------------------------------------------------------------------
// Kernel B: MFMA flash attention, TN=64, single barrier/chunk via register
// ping-pong double-buffered LDS V. XCD swizzle (all 8 m-tiles of a bh on
// one XCD -> K/V L2-resident; r5-measured FETCH 168->25 MB). Q/K frags
// direct from global (frag-order layouts). P C-layout -> B-frags via the
// r4-validated shfl_xor(32) exchange. O[d][m] += V(A,LDS) x P(B).
// ---------------------------------------------------------------------------
__global__ __launch_bounds__(256) void attn_kernel(
    const u16* __restrict__ Qb, const u16* __restrict__ Kb,
    const u16* __restrict__ Vb, u16* __restrict__ Ot) {
  const int blk = blockIdx.x;            // 0..1023
  const int xcd = blk & 7, j = blk >> 3;
  const int bh = (xcd << 4) | (j >> 3);  // 16 bh per XCD
  const int mt = j & 7;
  const int tid = threadIdx.x;
  const int wid = tid >> 6, lane = tid & 63;
  const int r32 = lane & 31, hh = lane >> 5;
  const int mw = mt * 128 + wid * 32;

  __shared__ __align__(16) u16 Vs[2][128 * 72];  // [d][64n], pad 72

  // Q B-frags: lane = col m, k = c (16 B contiguous)
  const u16* qp = Qb + ((size_t)bh * Nn + mw + r32) * 32;
  const bf16x8 qb0 = *(const bf16x8*)&qp[hh * 8];
  const bf16x8 qb1 = *(const bf16x8*)&qp[16 + hh * 8];

  const u16* kbase = Kb + (size_t)bh * Nn * 32;
  const u16* vbase = Vb + (size_t)bh * DV * Nn;

  // staging geometry: thread covers 4 uint4s, d = idx>>3, n8 = (idx&7)*8
  int sd[4], sn[4];
  #pragma unroll
  for (int i = 0; i < 4; ++i) {
    int idx = i * 256 + tid;
    sd[i] = idx >> 3; sn[i] = (idx & 7) * 8;
  }

  // prologue: stage chunk 0 into Vs[0]
  uint4 vreg[4];
  #pragma unroll
  for (int i = 0; i < 4; ++i)
    vreg[i] = *(const uint4*)&vbase[(size_t)sd[i] * Nn + sn[i]];
  #pragma unroll
  for (int i = 0; i < 4; ++i)
    *(uint4*)&Vs[0][sd[i] * 72 + sn[i]] = vreg[i];

  f32x16 o[4];                            // D[d][m], col m = r32
  #pragma unroll
  for (int t = 0; t < 4; ++t)
    #pragma unroll
    for (int r = 0; r < 16; ++r) o[t][r] = 0.0f;
  float lsum = 0.0f;

  for (int ch = 0; ch < 16; ++ch) {
    const int n0 = ch * 64;
    const int p = ch & 1;
    __syncthreads();  // Vs[p] writes visible; Vs[1-p] readers (prev it) done

    // issue next chunk's V loads early (overlap with compute below)
    if (ch < 15) {
      #pragma unroll
      for (int i = 0; i < 4; ++i)
        vreg[i] = *(const uint4*)&vbase[(size_t)sd[i] * Nn + n0 + 64 + sn[i]];
    }

    // K A-frags direct from global: rows n0+r32 and n0+32+r32
    const u16* kp0 = kbase + (size_t)(n0 + r32) * 32;
    const u16* kp1 = kbase + (size_t)(n0 + 32 + r32) * 32;
    bf16x8 ka0 = *(const bf16x8*)&kp0[hh * 8];
    bf16x8 ka1 = *(const bf16x8*)&kp0[16 + hh * 8];
    bf16x8 ka2 = *(const bf16x8*)&kp1[hh * 8];
    bf16x8 ka3 = *(const bf16x8*)&kp1[16 + hh * 8];

    // S^T: two 32n x 32m tiles
    f32x16 c0, c1;
    #pragma unroll
    for (int r = 0; r < 16; ++r) { c0[r] = 0.0f; c1[r] = 0.0f; }
    c0 = MFMA32(ka0, qb0, c0);
    c0 = MFMA32(ka1, qb1, c0);
    c1 = MFMA32(ka2, qb0, c1);
    c1 = MFMA32(ka3, qb1, c1);

    // softmax numerator p = 2^s; partial row-sum
    float csum = 0.0f;
    #pragma unroll
    for (int r = 0; r < 16; ++r) { c0[r] = fexp2(c0[r]); csum += c0[r]; }
    #pragma unroll
    for (int r = 0; r < 16; ++r) { c1[r] = fexp2(c1[r]); csum += c1[r]; }
    lsum += csum;

    // pack P and exchange halves -> B-operand frags (r4-validated algebra)
    u32 Pk[16], Rk[16];
    #pragma unroll
    for (int g = 0; g < 4; ++g) {
      Pk[2 * g]     = pkrn(c0[4 * g + 0], c0[4 * g + 1]);
      Pk[2 * g + 1] = pkrn(c0[4 * g + 2], c0[4 * g + 3]);
      Pk[8 + 2 * g]     = pkrn(c1[4 * g + 0], c1[4 * g + 1]);
      Pk[8 + 2 * g + 1] = pkrn(c1[4 * g + 2], c1[4 * g + 3]);
    }
    #pragma unroll
    for (int i = 0; i < 16; ++i) Rk[i] = __shfl_xor(Pk[i], 32, 64);

    union { u32 d[4]; bf16x8 v; } pb[4];
    #pragma unroll
    for (int q = 0; q < 2; ++q) {        // q=0 -> c0 (k 0..31), q=1 -> c1
      const int base = 8 * q;
      pb[2 * q].d[0] = hh ? Rk[base + 2] : Pk[base + 0];
      pb[2 * q].d[1] = hh ? Rk[base + 3] : Pk[base + 1];
      pb[2 * q].d[2] = hh ? Pk[base + 2] : Rk[base + 0];
      pb[2 * q].d[3] = hh ? Pk[base + 3] : Rk[base + 1];
      pb[2 * q + 1].d[0] = hh ? Rk[base + 6] : Pk[base + 4];
      pb[2 * q + 1].d[1] = hh ? Rk[base + 7] : Pk[base + 5];
      pb[2 * q + 1].d[2] = hh ? Pk[base + 6] : Rk[base + 4];
      pb[2 * q + 1].d[3] = hh ? Pk[base + 7] : Rk[base + 5];
    }

    // PV: O[d][m] += V(A from LDS) x P(B), 4 d-tiles x 4 k-steps
    #pragma unroll
    for (int t = 0; t < 4; ++t) {
      const u16* vrow = &Vs[p][(t * 32 + r32) * 72];
      #pragma unroll
      for (int s = 0; s < 4; ++s) {
        bf16x8 va = *(const bf16x8*)&vrow[s * 16 + hh * 8];
        o[t] = MFMA32(va, pb[s].v, o[t]);
      }
    }

    // park staged regs into the other buffer (loads long since landed)
    if (ch < 15) {
      #pragma unroll
      for (int i = 0; i < 4; ++i)
        *(uint4*)&Vs[1 - p][sd[i] * 72 + sn[i]] = vreg[i];
    }
  }

  // lane holds partial sums for col m = r32 over half the n-rows
  lsum += __shfl_xor(lsum, 32, 64);
  const float inv = 1.0f / lsum;
  const int m = mw + r32;
  const int b = bh >> 3, h = bh & 7;
  u16* obase = Ot + ((size_t)b * Nn + m) * 1024 + h * DV + 4 * hh;
  #pragma unroll
  for (int t = 0; t < 4; ++t) {
    #pragma unroll
    for (int g = 0; g < 4; ++g) {
      float v0 = fmaxf(o[t][4 * g + 0] * inv, 0.0f);
      float v1 = fmaxf(o[t][4 * g + 1] * inv, 0.0f);
      float v2 = fmaxf(o[t][4 * g + 2] * inv, 0.0f);
      float v3 = fmaxf(o[t][4 * g + 3] * inv, 0.0f);
      uint2 pk; pk.x = pkrn(v0, v1); pk.y = pkrn(v2, v3);
      *(uint2*)&obase[t * 32 + 8 * g] = pk;
    }
  }
}

// ---------------------------------------------------------------------------
// Kernel C: proj bf16 MFMA GEMM + fused bias/BN (r4 structure: Ot[b][m][ic],
// b128 row-major staging). L2 swizzle: the 4 oc-tiles of each (b,n0) run on
// consecutive blocks of one XCD -> the 256 KB Ot slice stays L2-resident.
// ---------------------------------------------------------------------------
__global__ __launch_bounds__(256) void proj_kernel(
    const u16* __restrict__ Ot, const float* __restrict__ pw,
    const float* __restrict__ pb, const float* __restrict__ bn_g,
    const float* __restrict__ bn_b, const float* __restrict__ bn_m,
    const float* __restrict__ bn_v, float* __restrict__ out) {
  const int blk = blockIdx.x;            // 0..511
  const int xcd = blk & 7, rr = blk >> 3;   // 64 blocks per XCD
  const int pairl = rr >> 2, oct = rr & 3;  // 16 (b,n0) pairs per XCD
  const int pair = xcd * 16 + pairl;        // 0..127
  const int b = pair >> 3, nt = pair & 7;
  const int n0 = nt * 128, oc0 = oct * 128;
  const int tid = threadIdx.x;
  const int wid = tid >> 6, lane = tid & 63;
  const int r32 = lane & 31, hh = lane >> 5;
  const int ocw = (wid >> 1) * 64, nw = (wid & 1) * 64;

  __shared__ __align__(16) u16 Ws[128 * 40];  // [oc][ic]
  __shared__ __align__(16) u16 Os[128 * 40];  // [n][ic]

  f32x16 o[2][2];
  #pragma unroll
  for (int t = 0; t < 2; ++t)
    #pragma unroll
    for (int u = 0; u < 2; ++u)
      #pragma unroll
      for (int r = 0; r < 16; ++r) o[t][u][r] = 0.0f;

  for (int ic0 = 0; ic0 < 1024; ic0 += 32) {
    __syncthreads();
    #pragma unroll
    for (int i = 0; i < 4; ++i) {       // stage W: 128x32 fp32 -> bf16
      int idx = i * 256 + tid;
      int row = idx >> 3, icq = (idx & 7) * 4;
      float4 wv = *(const float4*)&pw[(size_t)(oc0 + row) * 1024 + ic0 + icq];
      uint2 pk; pk.x = pkrn(wv.x, wv.y); pk.y = pkrn(wv.z, wv.w);
      *(uint2*)&Ws[row * 40 + icq] = pk;
    }
    #pragma unroll
    for (int i = 0; i < 2; ++i) {       // stage Ot rows: b128 copies
      int idx = i * 256 + tid;
      int row = idx >> 2, ic8 = (idx & 3) * 8;
      *(uint4*)&Os[row * 40 + ic8] =
          *(const uint4*)&Ot[((size_t)b * Nn + n0 + row) * 1024 + ic0 + ic8];
    }
    __syncthreads();

    #pragma unroll
    for (int s = 0; s < 2; ++s) {
      const int ko = s * 16 + hh * 8;
      bf16x8 a0 = *(const bf16x8*)&Ws[(ocw + r32) * 40 + ko];
      bf16x8 a1 = *(const bf16x8*)&Ws[(ocw + 32 + r32) * 40 + ko];
      bf16x8 b0 = *(const bf16x8*)&Os[(nw + r32) * 40 + ko];
      bf16x8 b1 = *(const bf16x8*)&Os[(nw + 32 + r32) * 40 + ko];
      o[0][0] = MFMA32(a0, b0, o[0][0]);
      o[0][1] = MFMA32(a0, b1, o[0][1]);
      o[1][0] = MFMA32(a1, b0, o[1][0]);
      o[1][1] = MFMA32(a1, b1, o[1][1]);
    }
  }

  #pragma unroll
  for (int t = 0; t < 2; ++t) {
    const int obase = oc0 + ocw + t * 32 + 4 * hh;
    #pragma unroll
    for (int g = 0; g < 4; ++g) {
      const int oc = obase + 8 * g;
      float4 gv = *(const float4*)&bn_g[oc];
      float4 vv = *(const float4*)&bn_v[oc];
      float4 bv = *(const float4*)&bn_b[oc];
      float4 mv = *(const float4*)&bn_m[oc];
      float4 pv = *(const float4*)&pb[oc];
      float inv4[4], add4[4];
      inv4[0] = gv.x * rsqrtf(vv.x + 1e-5f);
      inv4[1] = gv.y * rsqrtf(vv.y + 1e-5f);
      inv4[2] = gv.z * rsqrtf(vv.z + 1e-5f);
      inv4[3] = gv.w * rsqrtf(vv.w + 1e-5f);
      add4[0] = pv.x * inv4[0] + bv.x - mv.x * inv4[0];
      add4[1] = pv.y * inv4[1] + bv.y - mv.y * inv4[1];
      add4[2] = pv.z * inv4[2] + bv.z - mv.z * inv4[2];
      add4[3] = pv.w * inv4[3] + bv.w - mv.w * inv4[3];
      #pragma unroll
      for (int u = 0; u < 2; ++u) {
        const int n = n0 + nw + u * 32 + r32;
        #pragma unroll
        for (int i = 0; i < 4; ++i) {
          float val = o[t][u][4 * g + i] * inv4[i] + add4[i];
          out[((size_t)b * DIM + oc + i) * Nn + n] = val;
        }
      }
    }
  }
}

// ---------------------------------------------------------------------------
extern "C" void kernel_launch(void* const* d_in, const int* in_sizes, int n_in,
                              void* d_out, int out_size, void* d_ws,
                              size_t ws_size, hipStream_t stream) {
  const float* x      = (const float*)d_in[0];
  const float* qkv_w  = (const float*)d_in[1];
  const float* qkv_b  = (const float*)d_in[2];
  const float* proj_w = (const float*)d_in[3];
  const float* proj_b = (const float*)d_in[4];
  const float* bn_g   = (const float*)d_in[5];
  const float* bn_b   = (const float*)d_in[6];
  const float* bn_m   = (const float*)d_in[7];
  const float* bn_v   = (const float*)d_in[8];
  float* out = (float*)d_out;

  char* ws = (char*)d_ws;
  u16* Qb = (u16*)(ws);                  // 128*1024*32*2 =  8 MB
  u16* Kb = (u16*)(ws + 8388608);        //                  8 MB
  u16* Vb = (u16*)(ws + 16777216);       // 128*128*1024*2 = 32 MB
  u16* Ot = (u16*)(ws + 50331648);       // 16*1024*1024*2 = 32 MB  [b][m][ic]

  qkv_kernel<<<dim3(8, Bb * Hh), 256, 0, stream>>>(x, qkv_w, qkv_b, Qb, Kb, Vb);
  attn_kernel<<<dim3(1024), 256, 0, stream>>>(Qb, Kb, Vb, Ot);
  proj_kernel<<<dim3(512), 256, 0, stream>>>(
      Ot, proj_w, proj_b, bn_g, bn_b, bn_m, bn_v, out);
}

// Round 7
// 213.070 us; speedup vs baseline: 1.5027x; 1.0339x over previous
//
#include <hip/hip_runtime.h>
#include <math.h>

typedef unsigned short u16;
typedef unsigned int u32;

#define Bb   16
#define Hh   8
#define KD   32
#define DV   128
#define DIM  512
#define Nn   1024
#define OQKV 192
// SCALE * log2(e): QK logits in log2-domain; softmax exp -> v_exp_f32 (2^x)
#define SCALE2 0.25503490221320355f

typedef short bf16x8 __attribute__((ext_vector_type(8)));   // 4 VGPRs = 8 bf16
typedef float f32x16 __attribute__((ext_vector_type(16)));  // 32x32 C/D frag

#define MFMA32(a, b, c) __builtin_amdgcn_mfma_f32_32x32x16_bf16(a, b, c, 0, 0, 0)

__device__ __forceinline__ float fexp2(float x) {
#if __has_builtin(__builtin_amdgcn_exp2f)
  return __builtin_amdgcn_exp2f(x);
#else
  return exp2f(x);
#endif
}

__device__ __forceinline__ u16 f2bf_rn(float f) {
  return (u16)((__float_as_uint(f) + 0x8000u) >> 16);
}

// pack two f32 -> two bf16 in one dword. gfx950 has HW v_cvt_pk_bf16_f32
// (1 op); fallback: 2x v_add + v_perm (3 ops, half-up rounding).
#if __has_builtin(__builtin_amdgcn_cvt_pk_bf16_f32)
__device__ __forceinline__ u32 pk2(float lo, float hi) {
  auto r = __builtin_amdgcn_cvt_pk_bf16_f32(lo, hi);
  return __builtin_bit_cast(u32, r);
}
#else
__device__ __forceinline__ u32 pk2(float lo, float hi) {
  u32 a = __float_as_uint(lo) + 0x8000u;
  u32 b = __float_as_uint(hi) + 0x8000u;
  return __builtin_amdgcn_perm(b, a, 0x07060302);
}
#endif

// ---------------------------------------------------------------------------
// prep: one-shot conversions. pw -> Wb bf16 [512][1024]; qkv_w -> Wq bf16
// [8][192][64]; BN+bias fold -> invA/addB[512]. grid 512x256.
// ---------------------------------------------------------------------------
__global__ __launch_bounds__(256) void prep_kernel(
    const float* __restrict__ pw, const float* __restrict__ qw,
    const float* __restrict__ pb, const float* __restrict__ g,
    const float* __restrict__ bt, const float* __restrict__ mn,
    const float* __restrict__ vr, u16* __restrict__ Wb,
    u16* __restrict__ Wq, float* __restrict__ invA, float* __restrict__ addB) {
  const int tid = blockIdx.x * 256 + threadIdx.x;   // 0..131071
  {
    float4 v = *(const float4*)&pw[(size_t)tid * 4];
    uint2 pk; pk.x = pk2(v.x, v.y); pk.y = pk2(v.z, v.w);
    *(uint2*)&Wb[(size_t)tid * 4] = pk;
  }
  if (tid < 24576) {
    float4 v = *(const float4*)&qw[(size_t)tid * 4];
    uint2 pk; pk.x = pk2(v.x, v.y); pk.y = pk2(v.z, v.w);
    *(uint2*)&Wq[(size_t)tid * 4] = pk;
  }
  if (tid < DIM) {
    float inv = g[tid] * rsqrtf(vr[tid] + 1e-5f);
    invA[tid] = inv;
    addB[tid] = pb[tid] * inv + bt[tid] - mn[tid] * inv;
  }
}

// ---------------------------------------------------------------------------
// Kernel A: QKV bf16 MFMA GEMM. W staged from pre-converted Wq via b128;
// X staged pairwise (2 c-rows -> packed b32 stores). Outputs:
//   Qb[bh][n][32c] (SCALE*log2e folded), Kb[bh][n][32c], Vb[bh][d][1024n].
// ---------------------------------------------------------------------------
__global__ __launch_bounds__(256) void qkv_kernel(
    const float* __restrict__ x, const u16* __restrict__ Wq,
    const float* __restrict__ bias, u16* __restrict__ Qb,
    u16* __restrict__ Kb, u16* __restrict__ Vb) {
  const int nt = blockIdx.x, bh = blockIdx.y;
  const int b = bh >> 3, h = bh & 7;
  const int tid = threadIdx.x;
  const int wid = tid >> 6, lane = tid & 63;
  const int r32 = lane & 31, hh = lane >> 5;
  const int n0 = nt * 128;

  __shared__ __align__(16) u16 Ws[192 * 72];  // [o][c] bf16
  __shared__ __align__(16) u16 Xs[128 * 72];  // [n][c] bf16

  // stage W: b128 copies from Wq[h]
  const u16* wqp = Wq + (size_t)h * OQKV * 64;
  #pragma unroll
  for (int i = 0; i < 6; ++i) {
    int idx = i * 256 + tid;            // 0..1535 uint4s
    int o = idx >> 3, c8 = (idx & 7) * 8;
    *(uint4*)&Ws[o * 72 + c8] = *(const uint4*)&wqp[o * 64 + c8];
  }
  // stage X^T: two c-rows at a time, packed b32 stores
  const float* xp = x + ((size_t)b * DIM + h * 64) * Nn + n0;
  #pragma unroll
  for (int i = 0; i < 4; ++i) {
    int idx = i * 256 + tid;            // 0..1023
    int cp = idx >> 5, n4 = (idx & 31) * 4;
    const int c = 2 * cp;
    float4 a = *(const float4*)&xp[(size_t)c * Nn + n4];
    float4 d = *(const float4*)&xp[(size_t)(c + 1) * Nn + n4];
    *(u32*)&Xs[(n4 + 0) * 72 + c] = pk2(a.x, d.x);
    *(u32*)&Xs[(n4 + 1) * 72 + c] = pk2(a.y, d.y);
    *(u32*)&Xs[(n4 + 2) * 72 + c] = pk2(a.z, d.z);
    *(u32*)&Xs[(n4 + 3) * 72 + c] = pk2(a.w, d.w);
  }
  __syncthreads();

  f32x16 acc[6];
  #pragma unroll
  for (int t = 0; t < 6; ++t)
    #pragma unroll
    for (int r = 0; r < 16; ++r) acc[t][r] = 0.0f;

  const int nw = wid * 32;
  #pragma unroll
  for (int k = 0; k < 4; ++k) {
    const int ko = k * 16 + hh * 8;
    bf16x8 xb = *(const bf16x8*)&Xs[(nw + r32) * 72 + ko];
    #pragma unroll
    for (int t = 0; t < 6; ++t) {
      bf16x8 wa = *(const bf16x8*)&Ws[(t * 32 + r32) * 72 + ko];
      acc[t] = MFMA32(wa, xb, acc[t]);
    }
  }

  const int n = n0 + nw + r32;
  const float* bp = bias + h * OQKV;
  #pragma unroll
  for (int t = 0; t < 6; ++t) {
    #pragma unroll
    for (int g = 0; g < 4; ++g) {
      const int ob = t * 32 + 8 * g + 4 * hh;
      float4 bv = *(const float4*)&bp[ob];
      float v0 = acc[t][4 * g + 0] + bv.x;
      float v1 = acc[t][4 * g + 1] + bv.y;
      float v2 = acc[t][4 * g + 2] + bv.z;
      float v3 = acc[t][4 * g + 3] + bv.w;
      if (t == 0) {                       // Q, scaled by SCALE*log2e
        uint2 pk;
        pk.x = pk2(v0 * SCALE2, v1 * SCALE2);
        pk.y = pk2(v2 * SCALE2, v3 * SCALE2);
        *(uint2*)&Qb[((size_t)bh * Nn + n) * 32 + ob] = pk;
      } else if (t == 1) {                // K (c = ob - 32)
        uint2 pk; pk.x = pk2(v0, v1); pk.y = pk2(v2, v3);
        *(uint2*)&Kb[((size_t)bh * Nn + n) * 32 + ob - 32] = pk;
      } else {                            // V (d = ob - 64), row-major [d][n]
        const int d = ob - 64;
        Vb[((size_t)bh * DV + d + 0) * Nn + n] = f2bf_rn(v0);
        Vb[((size_t)bh * DV + d + 1) * Nn + n] = f2bf_rn(v1);
        Vb[((size_t)bh * DV + d + 2) * Nn + n] = f2bf_rn(v2);
        Vb[((size_t)bh * DV + d + 3) * Nn + n] = f2bf_rn(v3);
      }
    }
  }
}

// ---------------------------------------------------------------------------
// Kernel B: MFMA flash attention, TN=64, single barrier/chunk, register
// ping-pong dbuf LDS V, XCD swizzle. NEW: next-chunk K-fragment prefetch
// (K loads overlap exp/PV instead of stalling S after the barrier) and
// 1-op bf16 pair packing.
// ---------------------------------------------------------------------------
__global__ __launch_bounds__(256) void attn_kernel(
    const u16* __restrict__ Qb, const u16* __restrict__ Kb,
    const u16* __restrict__ Vb, u16* __restrict__ Ot) {
  const int blk = blockIdx.x;            // 0..1023
  const int xcd = blk & 7, j = blk >> 3;
  const int bh = (xcd << 4) | (j >> 3);  // 16 bh per XCD
  const int mt = j & 7;
  const int tid = threadIdx.x;
  const int wid = tid >> 6, lane = tid & 63;
  const int r32 = lane & 31, hh = lane >> 5;
  const int mw = mt * 128 + wid * 32;

  __shared__ __align__(16) u16 Vs[2][128 * 72];  // [d][64n], pad 72

  const u16* qp = Qb + ((size_t)bh * Nn + mw + r32) * 32;
  const bf16x8 qb0 = *(const bf16x8*)&qp[hh * 8];
  const bf16x8 qb1 = *(const bf16x8*)&qp[16 + hh * 8];

  const u16* kbase = Kb + (size_t)bh * Nn * 32;
  const u16* vbase = Vb + (size_t)bh * DV * Nn;

  int sd[4], sn[4];
  #pragma unroll
  for (int i = 0; i < 4; ++i) {
    int idx = i * 256 + tid;
    sd[i] = idx >> 3; sn[i] = (idx & 7) * 8;
  }

  // prologue: stage V chunk 0; load K chunk-0 fragments
  uint4 vreg[4];
  #pragma unroll
  for (int i = 0; i < 4; ++i)
    vreg[i] = *(const uint4*)&vbase[(size_t)sd[i] * Nn + sn[i]];
  #pragma unroll
  for (int i = 0; i < 4; ++i)
    *(uint4*)&Vs[0][sd[i] * 72 + sn[i]] = vreg[i];

  bf16x8 ka[4];
  {
    const u16* kp0 = kbase + (size_t)r32 * 32;
    const u16* kp1 = kbase + (size_t)(32 + r32) * 32;
    ka[0] = *(const bf16x8*)&kp0[hh * 8];
    ka[1] = *(const bf16x8*)&kp0[16 + hh * 8];
    ka[2] = *(const bf16x8*)&kp1[hh * 8];
    ka[3] = *(const bf16x8*)&kp1[16 + hh * 8];
  }

  f32x16 o[4];                            // D[d][m], col m = r32
  #pragma unroll
  for (int t = 0; t < 4; ++t)
    #pragma unroll
    for (int r = 0; r < 16; ++r) o[t][r] = 0.0f;
  float lsum = 0.0f;

  for (int ch = 0; ch < 16; ++ch) {
    const int n0 = ch * 64;
    const int p = ch & 1;
    __syncthreads();  // Vs[p] writes visible; Vs[1-p] readers done

    // next chunk's V loads (land during compute below)
    if (ch < 15) {
      #pragma unroll
      for (int i = 0; i < 4; ++i)
        vreg[i] = *(const uint4*)&vbase[(size_t)sd[i] * Nn + n0 + 64 + sn[i]];
    }

    // S^T: two 32n x 32m tiles (K frags were prefetched)
    f32x16 c0, c1;
    #pragma unroll
    for (int r = 0; r < 16; ++r) { c0[r] = 0.0f; c1[r] = 0.0f; }
    c0 = MFMA32(ka[0], qb0, c0);
    c0 = MFMA32(ka[1], qb1, c0);
    c1 = MFMA32(ka[2], qb0, c1);
    c1 = MFMA32(ka[3], qb1, c1);

    // prefetch next chunk's K fragments (overlaps exp/pack/PV)
    bf16x8 kn[4];
    if (ch < 15) {
      const u16* kp0 = kbase + (size_t)(n0 + 64 + r32) * 32;
      const u16* kp1 = kbase + (size_t)(n0 + 96 + r32) * 32;
      kn[0] = *(const bf16x8*)&kp0[hh * 8];
      kn[1] = *(const bf16x8*)&kp0[16 + hh * 8];
      kn[2] = *(const bf16x8*)&kp1[hh * 8];
      kn[3] = *(const bf16x8*)&kp1[16 + hh * 8];
    }

    // softmax numerator p = 2^s; partial row-sum
    float csum = 0.0f;
    #pragma unroll
    for (int r = 0; r < 16; ++r) { c0[r] = fexp2(c0[r]); csum += c0[r]; }
    #pragma unroll
    for (int r = 0; r < 16; ++r) { c1[r] = fexp2(c1[r]); csum += c1[r]; }
    lsum += csum;

    // pack P and exchange halves -> B-operand frags (validated algebra)
    u32 Pk[16], Rk[16];
    #pragma unroll
    for (int g = 0; g < 4; ++g) {
      Pk[2 * g]     = pk2(c0[4 * g + 0], c0[4 * g + 1]);
      Pk[2 * g + 1] = pk2(c0[4 * g + 2], c0[4 * g + 3]);
      Pk[8 + 2 * g]     = pk2(c1[4 * g + 0], c1[4 * g + 1]);
      Pk[8 + 2 * g + 1] = pk2(c1[4 * g + 2], c1[4 * g + 3]);
    }
    #pragma unroll
    for (int i = 0; i < 16; ++i) Rk[i] = __shfl_xor(Pk[i], 32, 64);

    union { u32 d[4]; bf16x8 v; } pb[4];
    #pragma unroll
    for (int q = 0; q < 2; ++q) {
      const int base = 8 * q;
      pb[2 * q].d[0] = hh ? Rk[base + 2] : Pk[base + 0];
      pb[2 * q].d[1] = hh ? Rk[base + 3] : Pk[base + 1];
      pb[2 * q].d[2] = hh ? Pk[base + 2] : Rk[base + 0];
      pb[2 * q].d[3] = hh ? Pk[base + 3] : Rk[base + 1];
      pb[2 * q + 1].d[0] = hh ? Rk[base + 6] : Pk[base + 4];
      pb[2 * q + 1].d[1] = hh ? Rk[base + 7] : Pk[base + 5];
      pb[2 * q + 1].d[2] = hh ? Pk[base + 6] : Rk[base + 4];
      pb[2 * q + 1].d[3] = hh ? Pk[base + 7] : Rk[base + 5];
    }

    // PV: O[d][m] += V(A from LDS) x P(B), 4 d-tiles x 4 k-steps
    #pragma unroll
    for (int t = 0; t < 4; ++t) {
      const u16* vrow = &Vs[p][(t * 32 + r32) * 72];
      #pragma unroll
      for (int s = 0; s < 4; ++s) {
        bf16x8 va = *(const bf16x8*)&vrow[s * 16 + hh * 8];
        o[t] = MFMA32(va, pb[s].v, o[t]);
      }
    }

    // park staged V regs into the other buffer; rotate K frags
    if (ch < 15) {
      #pragma unroll
      for (int i = 0; i < 4; ++i)
        *(uint4*)&Vs[1 - p][sd[i] * 72 + sn[i]] = vreg[i];
      #pragma unroll
      for (int i = 0; i < 4; ++i) ka[i] = kn[i];
    }
  }

  lsum += __shfl_xor(lsum, 32, 64);
  const float inv = 1.0f / lsum;
  const int m = mw + r32;
  const int b = bh >> 3, h = bh & 7;
  u16* obase = Ot + ((size_t)b * Nn + m) * 1024 + h * DV + 4 * hh;
  #pragma unroll
  for (int t = 0; t < 4; ++t) {
    #pragma unroll
    for (int g = 0; g < 4; ++g) {
      float v0 = fmaxf(o[t][4 * g + 0] * inv, 0.0f);
      float v1 = fmaxf(o[t][4 * g + 1] * inv, 0.0f);
      float v2 = fmaxf(o[t][4 * g + 2] * inv, 0.0f);
      float v3 = fmaxf(o[t][4 * g + 3] * inv, 0.0f);
      uint2 pk; pk.x = pk2(v0, v1); pk.y = pk2(v2, v3);
      *(uint2*)&obase[t * 32 + 8 * g] = pk;
    }
  }
}

// ---------------------------------------------------------------------------
// Kernel C: proj bf16 MFMA GEMM, BK=64 (16 chunks), pure-b128 staging from
// pre-converted Wb, epilogue from precomputed invA/addB. XCD swizzle.
// ---------------------------------------------------------------------------
__global__ __launch_bounds__(256) void proj_kernel(
    const u16* __restrict__ Ot, const u16* __restrict__ Wb,
    const float* __restrict__ invA, const float* __restrict__ addB,
    float* __restrict__ out) {
  const int blk = blockIdx.x;               // 0..511
  const int xcd = blk & 7, rr = blk >> 3;   // 64 blocks per XCD
  const int pairl = rr >> 2, oct = rr & 3;  // 16 (b,n0) pairs per XCD
  const int pair = xcd * 16 + pairl;        // 0..127
  const int b = pair >> 3, nt = pair & 7;
  const int n0 = nt * 128, oc0 = oct * 128;
  const int tid = threadIdx.x;
  const int wid = tid >> 6, lane = tid & 63;
  const int r32 = lane & 31, hh = lane >> 5;
  const int ocw = (wid >> 1) * 64, nw = (wid & 1) * 64;

  __shared__ __align__(16) u16 Ws[128 * 72];  // [oc][64 ic]
  __shared__ __align__(16) u16 Os[128 * 72];  // [n][64 ic]

  f32x16 o[2][2];
  #pragma unroll
  for (int t = 0; t < 2; ++t)
    #pragma unroll
    for (int u = 0; u < 2; ++u)
      #pragma unroll
      for (int r = 0; r < 16; ++r) o[t][u][r] = 0.0f;

  for (int ic0 = 0; ic0 < 1024; ic0 += 64) {
    __syncthreads();
    #pragma unroll
    for (int i = 0; i < 4; ++i) {       // stage W: 128x64 bf16, b128 copies
      int idx = i * 256 + tid;          // 0..1023
      int row = idx >> 3, c8 = (idx & 7) * 8;
      *(uint4*)&Ws[row * 72 + c8] =
          *(const uint4*)&Wb[(size_t)(oc0 + row) * 1024 + ic0 + c8];
    }
    #pragma unroll
    for (int i = 0; i < 4; ++i) {       // stage Ot: 128x64 bf16, b128 copies
      int idx = i * 256 + tid;
      int row = idx >> 3, c8 = (idx & 7) * 8;
      *(uint4*)&Os[row * 72 + c8] =
          *(const uint4*)&Ot[((size_t)b * Nn + n0 + row) * 1024 + ic0 + c8];
    }
    __syncthreads();

    #pragma unroll
    for (int s = 0; s < 4; ++s) {
      const int ko = s * 16 + hh * 8;
      bf16x8 a0 = *(const bf16x8*)&Ws[(ocw + r32) * 72 + ko];
      bf16x8 a1 = *(const bf16x8*)&Ws[(ocw + 32 + r32) * 72 + ko];
      bf16x8 b0 = *(const bf16x8*)&Os[(nw + r32) * 72 + ko];
      bf16x8 b1 = *(const bf16x8*)&Os[(nw + 32 + r32) * 72 + ko];
      o[0][0] = MFMA32(a0, b0, o[0][0]);
      o[0][1] = MFMA32(a0, b1, o[0][1]);
      o[1][0] = MFMA32(a1, b0, o[1][0]);
      o[1][1] = MFMA32(a1, b1, o[1][1]);
    }
  }

  #pragma unroll
  for (int t = 0; t < 2; ++t) {
    const int obase = oc0 + ocw + t * 32 + 4 * hh;
    #pragma unroll
    for (int g = 0; g < 4; ++g) {
      const int oc = obase + 8 * g;
      float4 iv = *(const float4*)&invA[oc];
      float4 av = *(const float4*)&addB[oc];
      #pragma unroll
      for (int u = 0; u < 2; ++u) {
        const int n = n0 + nw + u * 32 + r32;
        out[((size_t)b * DIM + oc + 0) * Nn + n] = o[t][u][4 * g + 0] * iv.x + av.x;
        out[((size_t)b * DIM + oc + 1) * Nn + n] = o[t][u][4 * g + 1] * iv.y + av.y;
        out[((size_t)b * DIM + oc + 2) * Nn + n] = o[t][u][4 * g + 2] * iv.z + av.z;
        out[((size_t)b * DIM + oc + 3) * Nn + n] = o[t][u][4 * g + 3] * iv.w + av.w;
      }
    }
  }
}

// ---------------------------------------------------------------------------
extern "C" void kernel_launch(void* const* d_in, const int* in_sizes, int n_in,
                              void* d_out, int out_size, void* d_ws,
                              size_t ws_size, hipStream_t stream) {
  const float* x      = (const float*)d_in[0];
  const float* qkv_w  = (const float*)d_in[1];
  const float* qkv_b  = (const float*)d_in[2];
  const float* proj_w = (const float*)d_in[3];
  const float* proj_b = (const float*)d_in[4];
  const float* bn_g   = (const float*)d_in[5];
  const float* bn_b   = (const float*)d_in[6];
  const float* bn_m   = (const float*)d_in[7];
  const float* bn_v   = (const float*)d_in[8];
  float* out = (float*)d_out;

  char* ws = (char*)d_ws;
  u16* Qb   = (u16*)(ws);                 // 8 MB
  u16* Kb   = (u16*)(ws + 8388608);       // 8 MB
  u16* Vb   = (u16*)(ws + 16777216);      // 32 MB
  u16* Ot   = (u16*)(ws + 50331648);      // 32 MB [b][m][ic]
  u16* Wb   = (u16*)(ws + 83886080);      // 1 MB  bf16 proj W
  u16* Wq   = (u16*)(ws + 84934656);      // 192 KB bf16 qkv W
  float* invA = (float*)(ws + 85131264);  // 2 KB
  float* addB = (float*)(ws + 85133312);  // 2 KB

  prep_kernel<<<dim3(512), 256, 0, stream>>>(
      proj_w, qkv_w, proj_b, bn_g, bn_b, bn_m, bn_v, Wb, Wq, invA, addB);
  qkv_kernel<<<dim3(8, Bb * Hh), 256, 0, stream>>>(x, Wq, qkv_b, Qb, Kb, Vb);
  attn_kernel<<<dim3(1024), 256, 0, stream>>>(Qb, Kb, Vb, Ot);
  proj_kernel<<<dim3(512), 256, 0, stream>>>(Ot, Wb, invA, addB, out);
}